// Round 2
// baseline (204.735 us; speedup 1.0000x reference)
//
#include <hip/hip_runtime.h>

#ifndef KE_CONST
#define KE_CONST 14.3996f
#endif

constexpr float R_MAX_C = 6.0f;
constexpr float LOG2E = 1.4426950408889634f;
constexpr float LN2 = 0.6931471805599453f;

// ---- raw-hardware transcendental helpers (no libm names -> no glibc clash) ----
__device__ __forceinline__ float fast_exp2(float x) { return __builtin_amdgcn_exp2f(x); }
__device__ __forceinline__ float fast_log2(float x) { return __builtin_amdgcn_logf(x); }
__device__ __forceinline__ float fast_exp(float x) { return __builtin_amdgcn_exp2f(x * LOG2E); }
// v_cos_f32: D = cos(S0 * 2*pi)  (input in revolutions)
__device__ __forceinline__ float cos_rev(float rev) { return __builtin_amdgcn_cosf(rev); }
__device__ __forceinline__ float fast_sqrt(float x) { return __builtin_amdgcn_sqrtf(x); }
__device__ __forceinline__ float fast_rcp(float x) { return __builtin_amdgcn_rcpf(x); }

__device__ __forceinline__ float softplus_f(float x) {
    // log(1 + e^x) = ln2 * log2(1 + 2^(x*log2e)); params are small (|x|<4)
    return LN2 * fast_log2(1.0f + fast_exp(x));
}

// Pack per-atom record: {x, y, z, Z_as_float} -> one aligned 16B gather target.
__global__ void pack_atoms_kernel(const float* __restrict__ R,
                                  const int* __restrict__ Z,
                                  float4* __restrict__ atoms, int n) {
    int t = blockIdx.x * blockDim.x + threadIdx.x;
    if (t < n) {
        atoms[t] = make_float4(R[3 * t + 0], R[3 * t + 1], R[3 * t + 2],
                               (float)Z[t]);
    }
}

struct EdgeParams {
    float ae, inv_an, c0, c1, c2, c3, e0, e1, e2, e3;
};

__device__ __forceinline__ float edge_term(float xi, float yi, float zi, float zfi,
                                           float xj, float yj, float zj, float zfj,
                                           const EdgeParams& p) {
    float dx = xj - xi, dy = yj - yi, dz = zj - zi;
    float dr = fast_sqrt(dx * dx + dy * dy + dz * dz);
    dr = fminf(fmaxf(dr, 0.02f), R_MAX_C);
    // cos(pi*dr/6) = v_cos(dr/12 revolutions)
    float cc = 0.5f * (cos_rev(dr * (1.0f / 12.0f)) + 1.0f);
    // Z^ae = exp2(ae * log2(Z)); Z in [1,49]
    float zpi = fast_exp2(p.ae * fast_log2(zfi));
    float zpj = fast_exp2(p.ae * fast_log2(zfj));
    float dist = dr * (zpi + zpj) * p.inv_an;
    float f = p.c0 * fast_exp(-p.e0 * dist) + p.c1 * fast_exp(-p.e1 * dist) +
              p.c2 * fast_exp(-p.e2 * dist) + p.c3 * fast_exp(-p.e3 * dist);
    return zfi * zfj * fast_rcp(dr) * f * cc;
}

template <bool PACKED>
__global__ __launch_bounds__(256) void edge_energy_kernel(
    const int* __restrict__ idx,            // [2*E]
    const float4* __restrict__ atoms,       // packed table (PACKED path)
    const float* __restrict__ R,            // fallback path
    const int* __restrict__ Z,              // fallback path
    const float* __restrict__ a_exp, const float* __restrict__ a_num,
    const float* __restrict__ coefficients, const float* __restrict__ exponents,
    const float* __restrict__ rep_scale,
    float* __restrict__ out, int nEdges) {
    EdgeParams p;
    p.ae = softplus_f(a_exp[0]);
    p.inv_an = fast_rcp(softplus_f(a_num[0]));
    p.c0 = softplus_f(coefficients[0]);
    p.c1 = softplus_f(coefficients[1]);
    p.c2 = softplus_f(coefficients[2]);
    p.c3 = softplus_f(coefficients[3]);
    p.e0 = softplus_f(exponents[0]);
    p.e1 = softplus_f(exponents[1]);
    p.e2 = softplus_f(exponents[2]);
    p.e3 = softplus_f(exponents[3]);
    const float scale = 0.5f * softplus_f(rep_scale[0]) * KE_CONST;

    const int gid = blockIdx.x * blockDim.x + threadIdx.x;
    const int stride = gridDim.x * blockDim.x;
    const int nvec = nEdges >> 2;
    const int4* __restrict__ idx_i4 = (const int4*)idx;
    const int4* __restrict__ idx_j4 = (const int4*)(idx + nEdges);

    float acc = 0.0f;
    for (int k = gid; k < nvec; k += stride) {
        int4 ii = idx_i4[k];
        int4 jj = idx_j4[k];
        int iv[4] = {ii.x, ii.y, ii.z, ii.w};
        int jv[4] = {jj.x, jj.y, jj.z, jj.w};
#pragma unroll
        for (int u = 0; u < 4; ++u) {
            int i = iv[u], j = jv[u];
            float xi, yi, zi, zfi, xj, yj, zj, zfj;
            if (PACKED) {
                float4 ai = atoms[i];
                float4 aj = atoms[j];
                xi = ai.x; yi = ai.y; zi = ai.z; zfi = ai.w;
                xj = aj.x; yj = aj.y; zj = aj.z; zfj = aj.w;
            } else {
                xi = R[3 * i]; yi = R[3 * i + 1]; zi = R[3 * i + 2];
                xj = R[3 * j]; yj = R[3 * j + 1]; zj = R[3 * j + 2];
                zfi = (float)Z[i]; zfj = (float)Z[j];
            }
            float e = edge_term(xi, yi, zi, zfi, xj, yj, zj, zfj, p);
            acc += (i != j) ? e : 0.0f;
        }
    }
    // tail (nEdges not multiple of 4)
    for (int t = (nvec << 2) + gid; t < nEdges; t += stride) {
        int i = idx[t], j = idx[nEdges + t];
        float xi, yi, zi, zfi, xj, yj, zj, zfj;
        if (PACKED) {
            float4 ai = atoms[i];
            float4 aj = atoms[j];
            xi = ai.x; yi = ai.y; zi = ai.z; zfi = ai.w;
            xj = aj.x; yj = aj.y; zj = aj.z; zfj = aj.w;
        } else {
            xi = R[3 * i]; yi = R[3 * i + 1]; zi = R[3 * i + 2];
            xj = R[3 * j]; yj = R[3 * j + 1]; zj = R[3 * j + 2];
            zfi = (float)Z[i]; zfj = (float)Z[j];
        }
        float e = edge_term(xi, yi, zi, zfi, xj, yj, zj, zfj, p);
        acc += (i != j) ? e : 0.0f;
    }

    // wave(64) shuffle reduce
#pragma unroll
    for (int off = 32; off > 0; off >>= 1) acc += __shfl_down(acc, off, 64);
    __shared__ float smem[4];  // 256 threads / 64
    const int lane = threadIdx.x & 63;
    const int wave = threadIdx.x >> 6;
    if (lane == 0) smem[wave] = acc;
    __syncthreads();
    if (threadIdx.x == 0) {
        float s = (smem[0] + smem[1]) + (smem[2] + smem[3]);
        atomicAdd(out, s * scale);
    }
}

extern "C" void kernel_launch(void* const* d_in, const int* in_sizes, int n_in,
                              void* d_out, int out_size, void* d_ws, size_t ws_size,
                              hipStream_t stream) {
    // setup_inputs order: R, Z, idx, box, offsets, a_exp, a_num, coefficients,
    //                     exponents, rep_scale
    const float* R = (const float*)d_in[0];
    const int* Z = (const int*)d_in[1];
    const int* idx = (const int*)d_in[2];
    // d_in[3] = box, d_in[4] = offsets : unused by the reference math
    const float* a_exp = (const float*)d_in[5];
    const float* a_num = (const float*)d_in[6];
    const float* coefficients = (const float*)d_in[7];
    const float* exponents = (const float*)d_in[8];
    const float* rep_scale = (const float*)d_in[9];

    const int nAtoms = in_sizes[0] / 3;
    const int nEdges = in_sizes[2] / 2;
    float* out = (float*)d_out;

    // d_out is re-poisoned to 0xAA before every timed launch -> zero it.
    (void)hipMemsetAsync(d_out, 0, sizeof(float), stream);

    const size_t need = (size_t)nAtoms * sizeof(float4);
    const int edge_blocks = 2048;  // 524288 threads, grid-stride
    if (ws_size >= need) {
        float4* atoms = (float4*)d_ws;
        pack_atoms_kernel<<<(nAtoms + 255) / 256, 256, 0, stream>>>(R, Z, atoms,
                                                                    nAtoms);
        edge_energy_kernel<true><<<edge_blocks, 256, 0, stream>>>(
            idx, atoms, R, Z, a_exp, a_num, coefficients, exponents, rep_scale,
            out, nEdges);
    } else {
        edge_energy_kernel<false><<<edge_blocks, 256, 0, stream>>>(
            idx, nullptr, R, Z, a_exp, a_num, coefficients, exponents, rep_scale,
            out, nEdges);
    }
}

// Round 4
// 204.337 us; speedup vs baseline: 1.0019x; 1.0019x over previous
//
#include <hip/hip_runtime.h>

#ifndef KE_CONST
#define KE_CONST 14.3996f
#endif

constexpr float R_MAX_C = 6.0f;
constexpr float LOG2E = 1.4426950408889634f;
constexpr float LN2 = 0.6931471805599453f;

// native clang vector type (works with __builtin_nontemporal_load, unlike
// HIP_vector_type-based int4)
typedef int vint4 __attribute__((ext_vector_type(4)));

// ---- raw-hardware transcendentals (no libm names -> no glibc clash) ----
__device__ __forceinline__ float fast_exp2(float x) { return __builtin_amdgcn_exp2f(x); }
__device__ __forceinline__ float fast_log2(float x) { return __builtin_amdgcn_logf(x); }
__device__ __forceinline__ float fast_exp(float x) { return __builtin_amdgcn_exp2f(x * LOG2E); }
// v_cos_f32: D = cos(S0 * 2*pi) (input in revolutions)
__device__ __forceinline__ float cos_rev(float rev) { return __builtin_amdgcn_cosf(rev); }
__device__ __forceinline__ float fast_sqrt(float x) { return __builtin_amdgcn_sqrtf(x); }
__device__ __forceinline__ float fast_rcp(float x) { return __builtin_amdgcn_rcpf(x); }

__device__ __forceinline__ float softplus_f(float x) {
    return LN2 * fast_log2(1.0f + fast_exp(x));
}

// Pack per-atom record {x,y,z,Zf} -> one aligned 16B gather; also init out=0
// (d_out is re-poisoned to 0xAA before every timed launch).
__global__ void pack_atoms_kernel(const float* __restrict__ R,
                                  const int* __restrict__ Z,
                                  float4* __restrict__ atoms, int n,
                                  float* __restrict__ out) {
    int t = blockIdx.x * blockDim.x + threadIdx.x;
    if (t == 0) out[0] = 0.0f;
    if (t < n) {
        atoms[t] = make_float4(R[3 * t + 0], R[3 * t + 1], R[3 * t + 2],
                               (float)Z[t]);
    }
}

struct EdgeParams {
    float ae, inv_an, c0, c1, c2, c3, e0, e1, e2, e3;
};

__device__ __forceinline__ float edge_term(const float4& ai, const float4& aj,
                                           const EdgeParams& p) {
    float dx = aj.x - ai.x, dy = aj.y - ai.y, dz = aj.z - ai.z;
    float dr = fast_sqrt(dx * dx + dy * dy + dz * dz);
    dr = fminf(fmaxf(dr, 0.02f), R_MAX_C);
    // cos(pi*dr/6) = v_cos(dr/12 revolutions)
    float cc = 0.5f * (cos_rev(dr * (1.0f / 12.0f)) + 1.0f);
    float zpi = fast_exp2(p.ae * fast_log2(ai.w));
    float zpj = fast_exp2(p.ae * fast_log2(aj.w));
    float dist = dr * (zpi + zpj) * p.inv_an;
    float f = p.c0 * fast_exp(-p.e0 * dist) + p.c1 * fast_exp(-p.e1 * dist) +
              p.c2 * fast_exp(-p.e2 * dist) + p.c3 * fast_exp(-p.e3 * dist);
    return ai.w * aj.w * fast_rcp(dr) * f * cc;
}

__device__ __forceinline__ EdgeParams load_params(
    const float* a_exp, const float* a_num, const float* coefficients,
    const float* exponents) {
    EdgeParams p;
    p.ae = softplus_f(a_exp[0]);
    p.inv_an = fast_rcp(softplus_f(a_num[0]));
    p.c0 = softplus_f(coefficients[0]);
    p.c1 = softplus_f(coefficients[1]);
    p.c2 = softplus_f(coefficients[2]);
    p.c3 = softplus_f(coefficients[3]);
    p.e0 = softplus_f(exponents[0]);
    p.e1 = softplus_f(exponents[1]);
    p.e2 = softplus_f(exponents[2]);
    p.e3 = softplus_f(exponents[3]);
    return p;
}

// One-shot: each thread handles exactly 8 edges. All 16 gathers issued before
// compute -> 16 outstanding vmem ops/wave for latency hiding.
__global__ __launch_bounds__(256, 4) void edge_energy_kernel(
    const int* __restrict__ idx,        // [2*E]
    const float4* __restrict__ atoms,   // packed table
    const float* __restrict__ a_exp, const float* __restrict__ a_num,
    const float* __restrict__ coefficients, const float* __restrict__ exponents,
    const float* __restrict__ rep_scale,
    float* __restrict__ out, int nEdges) {
    EdgeParams p = load_params(a_exp, a_num, coefficients, exponents);
    const float scale = 0.5f * softplus_f(rep_scale[0]) * KE_CONST;

    const long long tid = (long long)blockIdx.x * blockDim.x + threadIdx.x;
    const long long base = tid * 8;

    float acc = 0.0f;
    if (base + 8 <= (long long)nEdges) {
        const vint4* __restrict__ i4 = (const vint4*)(idx) + (base >> 2);
        const vint4* __restrict__ j4 = (const vint4*)(idx + nEdges) + (base >> 2);
        // idx stream is read once -> non-temporal, keep L2 for the atom table
        vint4 ia = __builtin_nontemporal_load(i4);
        vint4 ib = __builtin_nontemporal_load(i4 + 1);
        vint4 ja = __builtin_nontemporal_load(j4);
        vint4 jb = __builtin_nontemporal_load(j4 + 1);
        int ii[8] = {ia.x, ia.y, ia.z, ia.w, ib.x, ib.y, ib.z, ib.w};
        int jj[8] = {ja.x, ja.y, ja.z, ja.w, jb.x, jb.y, jb.z, jb.w};
        float4 A[8], B[8];
#pragma unroll
        for (int u = 0; u < 8; ++u) {
            A[u] = atoms[ii[u]];
            B[u] = atoms[jj[u]];
        }
#pragma unroll
        for (int u = 0; u < 8; ++u) {
            float e = edge_term(A[u], B[u], p);
            acc += (ii[u] != jj[u]) ? e : 0.0f;
        }
    } else if (base < (long long)nEdges) {
        for (long long t = base; t < (long long)nEdges; ++t) {
            int i = idx[t], j = idx[nEdges + t];
            float4 ai = atoms[i];
            float4 aj = atoms[j];
            float e = edge_term(ai, aj, p);
            acc += (i != j) ? e : 0.0f;
        }
    }

    // wave(64) shuffle reduce -> block -> one atomic
#pragma unroll
    for (int off = 32; off > 0; off >>= 1) acc += __shfl_down(acc, off, 64);
    __shared__ float smem[4];
    const int lane = threadIdx.x & 63;
    const int wave = threadIdx.x >> 6;
    if (lane == 0) smem[wave] = acc;
    __syncthreads();
    if (threadIdx.x == 0) {
        float s = (smem[0] + smem[1]) + (smem[2] + smem[3]);
        atomicAdd(out, s * scale);
    }
}

extern "C" void kernel_launch(void* const* d_in, const int* in_sizes, int n_in,
                              void* d_out, int out_size, void* d_ws, size_t ws_size,
                              hipStream_t stream) {
    // setup_inputs order: R, Z, idx, box, offsets, a_exp, a_num, coefficients,
    //                     exponents, rep_scale
    const float* R = (const float*)d_in[0];
    const int* Z = (const int*)d_in[1];
    const int* idx = (const int*)d_in[2];
    const float* a_exp = (const float*)d_in[5];
    const float* a_num = (const float*)d_in[6];
    const float* coefficients = (const float*)d_in[7];
    const float* exponents = (const float*)d_in[8];
    const float* rep_scale = (const float*)d_in[9];

    const int nAtoms = in_sizes[0] / 3;
    const int nEdges = in_sizes[2] / 2;
    float* out = (float*)d_out;

    float4* atoms = (float4*)d_ws;  // needs nAtoms*16 bytes (1.6 MB @ 100k)
    pack_atoms_kernel<<<(nAtoms + 255) / 256, 256, 0, stream>>>(R, Z, atoms,
                                                                nAtoms, out);
    // 8 edges per thread, exact cover (E = 6.4M -> 3125 blocks of 256)
    const int edges_per_block = 256 * 8;
    const int blocks = (nEdges + edges_per_block - 1) / edges_per_block;
    edge_energy_kernel<<<blocks, 256, 0, stream>>>(
        idx, atoms, a_exp, a_num, coefficients, exponents, rep_scale, out,
        nEdges);
}

// Round 5
// 197.551 us; speedup vs baseline: 1.0364x; 1.0344x over previous
//
#include <hip/hip_runtime.h>

#ifndef KE_CONST
#define KE_CONST 14.3996f
#endif

constexpr float R_MAX_C = 6.0f;
constexpr float LOG2E = 1.4426950408889634f;
constexpr float LN2 = 0.6931471805599453f;

typedef int vint4 __attribute__((ext_vector_type(4)));

// ---- raw-hardware transcendentals (no libm names -> no glibc clash) ----
__device__ __forceinline__ float fast_exp2(float x) { return __builtin_amdgcn_exp2f(x); }
__device__ __forceinline__ float fast_log2(float x) { return __builtin_amdgcn_logf(x); }
__device__ __forceinline__ float fast_exp(float x) { return __builtin_amdgcn_exp2f(x * LOG2E); }
// v_cos_f32: D = cos(S0 * 2*pi) (input in revolutions)
__device__ __forceinline__ float cos_rev(float rev) { return __builtin_amdgcn_cosf(rev); }
__device__ __forceinline__ float fast_sqrt(float x) { return __builtin_amdgcn_sqrtf(x); }
__device__ __forceinline__ float fast_rcp(float x) { return __builtin_amdgcn_rcpf(x); }

__device__ __forceinline__ float softplus_f(float x) {
    return LN2 * fast_log2(1.0f + fast_exp(x));
}

// Pack per-atom record {x,y,z,Zf} -> one aligned 16B gather; also init out=0
// (d_out is re-poisoned to 0xAA before every timed launch).
__global__ void pack_atoms_kernel(const float* __restrict__ R,
                                  const int* __restrict__ Z,
                                  float4* __restrict__ atoms, int n,
                                  float* __restrict__ out) {
    int t = blockIdx.x * blockDim.x + threadIdx.x;
    if (t == 0) out[0] = 0.0f;
    if (t < n) {
        atoms[t] = make_float4(R[3 * t + 0], R[3 * t + 1], R[3 * t + 2],
                               (float)Z[t]);
    }
}

struct EdgeParams {
    float inv_an, c0, c1, c2, c3, e0, e1, e2, e3;
};

// zpow_lut[z] = z^ae, read from LDS (indices in [1,50): <=2-way bank alias = free)
__device__ __forceinline__ float edge_term(const float4& ai, const float4& aj,
                                           const EdgeParams& p,
                                           const float* __restrict__ zpow_lut) {
    float dx = aj.x - ai.x, dy = aj.y - ai.y, dz = aj.z - ai.z;
    float dr = fast_sqrt(dx * dx + dy * dy + dz * dz);
    dr = fminf(fmaxf(dr, 0.02f), R_MAX_C);
    // cos(pi*dr/6) = v_cos(dr/12 revolutions)
    float cc = 0.5f * (cos_rev(dr * (1.0f / 12.0f)) + 1.0f);
    float zpi = zpow_lut[(int)ai.w];
    float zpj = zpow_lut[(int)aj.w];
    float dist = dr * (zpi + zpj) * p.inv_an;
    float f = p.c0 * fast_exp(-p.e0 * dist) + p.c1 * fast_exp(-p.e1 * dist) +
              p.c2 * fast_exp(-p.e2 * dist) + p.c3 * fast_exp(-p.e3 * dist);
    return ai.w * aj.w * fast_rcp(dr) * f * cc;
}

// One-shot: 8 edges/thread. All 16 gathers forced to issue before compute via
// sched_barrier (VGPR ~= 110-128 is the *intended* cost: 4 waves/SIMD, each
// with 16 outstanding 16B gathers -> max per-CU miss-level parallelism).
__global__ __launch_bounds__(256, 4) void edge_energy_kernel(
    const int* __restrict__ idx,        // [2*E]
    const float4* __restrict__ atoms,   // packed table
    const float* __restrict__ a_exp, const float* __restrict__ a_num,
    const float* __restrict__ coefficients, const float* __restrict__ exponents,
    const float* __restrict__ rep_scale,
    float* __restrict__ out, int nEdges) {
    __shared__ float zpow_lut[64];
    __shared__ float smem[4];

    const float ae = softplus_f(a_exp[0]);
    // fill Z^ae LUT (Z in [1,50); slot 0 unused but defined)
    if (threadIdx.x < 64) {
        float z = (float)(threadIdx.x == 0 ? 1 : threadIdx.x);
        zpow_lut[threadIdx.x] = fast_exp2(ae * fast_log2(z));
    }

    EdgeParams p;
    p.inv_an = fast_rcp(softplus_f(a_num[0]));
    p.c0 = softplus_f(coefficients[0]);
    p.c1 = softplus_f(coefficients[1]);
    p.c2 = softplus_f(coefficients[2]);
    p.c3 = softplus_f(coefficients[3]);
    p.e0 = softplus_f(exponents[0]);
    p.e1 = softplus_f(exponents[1]);
    p.e2 = softplus_f(exponents[2]);
    p.e3 = softplus_f(exponents[3]);
    const float scale = 0.5f * softplus_f(rep_scale[0]) * KE_CONST;
    __syncthreads();

    const long long tid = (long long)blockIdx.x * blockDim.x + threadIdx.x;
    const long long base = tid * 8;

    float acc = 0.0f;
    if (base + 8 <= (long long)nEdges) {
        const vint4* __restrict__ i4 = (const vint4*)(idx) + (base >> 2);
        const vint4* __restrict__ j4 = (const vint4*)(idx + nEdges) + (base >> 2);
        vint4 ia = i4[0];
        vint4 ib = i4[1];
        vint4 ja = j4[0];
        vint4 jb = j4[1];
        int ii[8] = {ia.x, ia.y, ia.z, ia.w, ib.x, ib.y, ib.z, ib.w};
        int jj[8] = {ja.x, ja.y, ja.z, ja.w, jb.x, jb.y, jb.z, jb.w};
        float4 A[8], B[8];
#pragma unroll
        for (int u = 0; u < 8; ++u) {
            A[u] = atoms[ii[u]];
            B[u] = atoms[jj[u]];
        }
        // HARD FENCE: nothing moves across. Forces all 16 gathers issued (and
        // their 64 dest VGPRs live) before any edge_term compute is scheduled.
        __builtin_amdgcn_sched_barrier(0);
#pragma unroll
        for (int u = 0; u < 8; ++u) {
            float e = edge_term(A[u], B[u], p, zpow_lut);
            acc += (ii[u] != jj[u]) ? e : 0.0f;
        }
    } else if (base < (long long)nEdges) {
        for (long long t = base; t < (long long)nEdges; ++t) {
            int i = idx[t], j = idx[nEdges + t];
            float4 ai = atoms[i];
            float4 aj = atoms[j];
            float e = edge_term(ai, aj, p, zpow_lut);
            acc += (i != j) ? e : 0.0f;
        }
    }

    // wave(64) shuffle reduce -> block -> one atomic
#pragma unroll
    for (int off = 32; off > 0; off >>= 1) acc += __shfl_down(acc, off, 64);
    const int lane = threadIdx.x & 63;
    const int wave = threadIdx.x >> 6;
    if (lane == 0) smem[wave] = acc;
    __syncthreads();
    if (threadIdx.x == 0) {
        float s = (smem[0] + smem[1]) + (smem[2] + smem[3]);
        atomicAdd(out, s * scale);
    }
}

extern "C" void kernel_launch(void* const* d_in, const int* in_sizes, int n_in,
                              void* d_out, int out_size, void* d_ws, size_t ws_size,
                              hipStream_t stream) {
    // setup_inputs order: R, Z, idx, box, offsets, a_exp, a_num, coefficients,
    //                     exponents, rep_scale
    const float* R = (const float*)d_in[0];
    const int* Z = (const int*)d_in[1];
    const int* idx = (const int*)d_in[2];
    const float* a_exp = (const float*)d_in[5];
    const float* a_num = (const float*)d_in[6];
    const float* coefficients = (const float*)d_in[7];
    const float* exponents = (const float*)d_in[8];
    const float* rep_scale = (const float*)d_in[9];

    const int nAtoms = in_sizes[0] / 3;
    const int nEdges = in_sizes[2] / 2;
    float* out = (float*)d_out;

    float4* atoms = (float4*)d_ws;  // needs nAtoms*16 bytes (1.6 MB @ 100k)
    pack_atoms_kernel<<<(nAtoms + 255) / 256, 256, 0, stream>>>(R, Z, atoms,
                                                                nAtoms, out);
    // 8 edges per thread, exact cover (E = 6.4M -> 3125 blocks of 256)
    const int edges_per_block = 256 * 8;
    const int blocks = (nEdges + edges_per_block - 1) / edges_per_block;
    edge_energy_kernel<<<blocks, 256, 0, stream>>>(
        idx, atoms, a_exp, a_num, coefficients, exponents, rep_scale, out,
        nEdges);
}